// Round 1
// baseline (277.760 us; speedup 1.0000x reference)
//
#include <hip/hip_runtime.h>
#include <hip/hip_fp16.h>

typedef _Float16 f16x8 __attribute__((ext_vector_type(8)));
typedef float f32x4 __attribute__((ext_vector_type(4)));

#define NEGV (-1000000000.0f)

// ---------- weight transpose f32 -> f16: WT[n][k] = W[k][n], both 512x512 ----------
__global__ __launch_bounds__(256) void wtrans_kernel(const float* __restrict__ W,
                                                     __half* __restrict__ WT) {
  __shared__ float t[32][33];
  int n0 = blockIdx.x * 32, k0 = blockIdx.y * 32;
  int tx = threadIdx.x, ty = threadIdx.y;  // (32,8)
#pragma unroll
  for (int i = 0; i < 4; i++)
    t[ty + i * 8][tx] = W[(size_t)(k0 + ty + i * 8) * 512 + n0 + tx];
  __syncthreads();
#pragma unroll
  for (int i = 0; i < 4; i++)
    WT[(size_t)(n0 + ty + i * 8) * 512 + k0 + tx] = __float2half(t[tx][ty + i * 8]);
}

// ---------- V transpose: Vout[4096][512] f16 -> Vt[32][64][1024] ----------
__global__ __launch_bounds__(256) void vtrans_kernel(const __half* __restrict__ V,
                                                     __half* __restrict__ Vt) {
  __shared__ __half t[64][72];
  int bh = blockIdx.y, b = bh >> 3, h = bh & 7;
  int s0 = blockIdx.x * 64;
  int tx = threadIdx.x, ty = threadIdx.y;  // (64,4)
#pragma unroll
  for (int i = 0; i < 16; i++)
    t[ty + i * 4][tx] = V[(size_t)(b * 1024 + s0 + ty + i * 4) * 512 + h * 64 + tx];
  __syncthreads();
#pragma unroll
  for (int i = 0; i < 16; i++)
    Vt[((size_t)bh * 64 + ty + i * 4) * 1024 + s0 + tx] = t[tx][ty + i * 4];
}

// ---------- GEMM: C[4096][N] f16 = A[4096][512] @ (Bt[N][512])^T ----------
template <int AF32>
__global__ __launch_bounds__(256) void gemm_kernel(const void* __restrict__ Ap,
                                                   const __half* __restrict__ Bt,
                                                   __half* __restrict__ C, int N) {
  __shared__ __align__(16) _Float16 As[128][40];
  __shared__ __align__(16) _Float16 Bs[128][40];
  int tid = threadIdx.x;
  int wave = tid >> 6, lane = tid & 63;
  int lg = lane >> 4, l15 = lane & 15;
  int wm = (wave >> 1) * 64, wn = (wave & 1) * 64;
  int bm0 = blockIdx.y * 128, bn0 = blockIdx.x * 128;
  int srow = tid >> 1, sseg = (tid & 1) * 16;
  const float* Af = (const float*)Ap;
  const __half* Ah = (const __half*)Ap;
  f32x4 acc[4][4];
#pragma unroll
  for (int i = 0; i < 4; i++)
#pragma unroll
    for (int j = 0; j < 4; j++) acc[i][j] = (f32x4){0.f, 0.f, 0.f, 0.f};

  for (int kt = 0; kt < 16; kt++) {
    int k0 = kt * 32;
    if (AF32) {
      const float* s = Af + (size_t)(bm0 + srow) * 512 + k0 + sseg;
      _Float16* d = &As[srow][sseg];
#pragma unroll
      for (int i = 0; i < 16; i += 4) {
        float4 v = *(const float4*)(s + i);
        d[i] = (_Float16)v.x; d[i + 1] = (_Float16)v.y;
        d[i + 2] = (_Float16)v.z; d[i + 3] = (_Float16)v.w;
      }
    } else {
      const __half* s = Ah + (size_t)(bm0 + srow) * 512 + k0 + sseg;
      *(uint4*)&As[srow][sseg] = *(const uint4*)s;
      *(uint4*)(&As[srow][sseg] + 8) = *(const uint4*)(s + 8);
    }
    {
      const __half* s = Bt + (size_t)(bn0 + srow) * 512 + k0 + sseg;
      *(uint4*)&Bs[srow][sseg] = *(const uint4*)s;
      *(uint4*)(&Bs[srow][sseg] + 8) = *(const uint4*)(s + 8);
    }
    __syncthreads();
    f16x8 af[4], bf[4];
#pragma unroll
    for (int i = 0; i < 4; i++) af[i] = *(const f16x8*)&As[wm + i * 16 + l15][lg * 8];
#pragma unroll
    for (int j = 0; j < 4; j++) bf[j] = *(const f16x8*)&Bs[wn + j * 16 + l15][lg * 8];
#pragma unroll
    for (int i = 0; i < 4; i++)
#pragma unroll
      for (int j = 0; j < 4; j++)
        acc[i][j] = __builtin_amdgcn_mfma_f32_16x16x32_f16(af[i], bf[j], acc[i][j], 0, 0, 0);
    __syncthreads();
  }
#pragma unroll
  for (int i = 0; i < 4; i++)
#pragma unroll
    for (int j = 0; j < 4; j++)
#pragma unroll
      for (int r = 0; r < 4; r++) {
        int m = bm0 + wm + i * 16 + lg * 4 + r;
        int n = bn0 + wn + j * 16 + l15;
        C[(size_t)m * N + n] = __float2half(acc[i][j][r]);
      }
}

// ---------- fused attention ----------
// grid (32 qtiles, 32 bh), block 256 (4 waves). Wave w owns keys [w*256, w*256+256).
__global__ __launch_bounds__(256, 2) void attn_kernel(
    const __half* __restrict__ QQ2, const __half* __restrict__ KK2,
    const __half* __restrict__ Vt, const int* __restrict__ am,
    const int* __restrict__ bmk, float* __restrict__ attn_out,
    __half* __restrict__ CTX) {
  int bh = blockIdx.y, b = bh >> 3, h = bh & 7;
  int q0 = blockIdx.x * 32;
  int tid = threadIdx.x;
  int wave = tid >> 6, lane = tid & 63;
  int lg = lane >> 4, l15 = lane & 15;

  __shared__ __align__(16) _Float16 P[4][32][264];  // 67.6 KB, padded (stride 528B)
  __shared__ float redmax[4][32], redsum[4][32];

  // Q / Q2 fragments (A-operand: row = lane&15, k = (lane>>4)*8+j)
  f16x8 qf[2][2], q2f[2][2];
  {
    const __half* Qb = QQ2 + ((size_t)(b * 1024 + q0)) * 1024 + h * 64;
#pragma unroll
    for (int mi = 0; mi < 2; mi++)
#pragma unroll
      for (int ks = 0; ks < 2; ks++) {
        const __half* p = Qb + (size_t)(mi * 16 + l15) * 1024 + ks * 32 + lg * 8;
        qf[mi][ks] = *(const f16x8*)p;
        q2f[mi][ks] = *(const f16x8*)(p + 512);
      }
  }

  float sc[2][16][4];
  const __half* Kb = KK2 + ((size_t)(b * 1024)) * 1024 + h * 64;
  const int kw = wave * 256;
  const size_t mrow = (size_t)b * 1024 + q0;
#pragma unroll
  for (int kt = 0; kt < 16; kt++) {
    int kc = kw + kt * 16;
    f16x8 kf[2], k2f[2];
#pragma unroll
    for (int ks = 0; ks < 2; ks++) {
      const __half* p = Kb + (size_t)(kc + l15) * 1024 + ks * 32 + lg * 8;
      kf[ks] = *(const f16x8*)p;
      k2f[ks] = *(const f16x8*)(p + 512);
    }
#pragma unroll
    for (int mi = 0; mi < 2; mi++) {
      f32x4 s1 = (f32x4){0.f, 0.f, 0.f, 0.f};
      f32x4 s2 = (f32x4){0.f, 0.f, 0.f, 0.f};
      s1 = __builtin_amdgcn_mfma_f32_16x16x32_f16(qf[mi][0], kf[0], s1, 0, 0, 0);
      s1 = __builtin_amdgcn_mfma_f32_16x16x32_f16(qf[mi][1], kf[1], s1, 0, 0, 0);
      s2 = __builtin_amdgcn_mfma_f32_16x16x32_f16(q2f[mi][0], k2f[0], s2, 0, 0, 0);
      s2 = __builtin_amdgcn_mfma_f32_16x16x32_f16(q2f[mi][1], k2f[1], s2, 0, 0, 0);
      int col = kc + l15;
#pragma unroll
      for (int r = 0; r < 4; r++) {
        int row = mi * 16 + lg * 4 + r;  // C-layout: row=(lane>>4)*4+reg, col=lane&15
        size_t mix = (mrow + row) * 1024 + col;
        float bias = bmk[mix] ? NEGV : s2[r];
        sc[mi][kt][r] = am[mix] ? NEGV : (s1[r] * 0.125f + bias);
      }
    }
  }

  // row max: per-lane over kt, xor-shuffle within 16-lane group, cross-wave via LDS
#pragma unroll
  for (int mi = 0; mi < 2; mi++)
#pragma unroll
    for (int r = 0; r < 4; r++) {
      float m = sc[mi][0][r];
#pragma unroll
      for (int kt = 1; kt < 16; kt++) m = fmaxf(m, sc[mi][kt][r]);
#pragma unroll
      for (int o = 1; o < 16; o <<= 1) m = fmaxf(m, __shfl_xor(m, o));
      if (l15 == 0) redmax[wave][mi * 16 + lg * 4 + r] = m;
    }
  __syncthreads();
  float mfin[2][4];
#pragma unroll
  for (int mi = 0; mi < 2; mi++)
#pragma unroll
    for (int r = 0; r < 4; r++) {
      int row = mi * 16 + lg * 4 + r;
      mfin[mi][r] = fmaxf(fmaxf(redmax[0][row], redmax[1][row]),
                          fmaxf(redmax[2][row], redmax[3][row]));
    }
  // exp + row sum
#pragma unroll
  for (int mi = 0; mi < 2; mi++)
#pragma unroll
    for (int r = 0; r < 4; r++) {
      float s = 0.f;
#pragma unroll
      for (int kt = 0; kt < 16; kt++) {
        float p = __expf(sc[mi][kt][r] - mfin[mi][r]);
        sc[mi][kt][r] = p;
        s += p;
      }
#pragma unroll
      for (int o = 1; o < 16; o <<= 1) s += __shfl_xor(s, o);
      if (l15 == 0) redsum[wave][mi * 16 + lg * 4 + r] = s;
    }
  __syncthreads();
  float inv[2][4];
#pragma unroll
  for (int mi = 0; mi < 2; mi++)
#pragma unroll
    for (int r = 0; r < 4; r++) {
      int row = mi * 16 + lg * 4 + r;
      inv[mi][r] = 1.0f / (redsum[0][row] + redsum[1][row] + redsum[2][row] + redsum[3][row]);
    }
  // write attn (f32, d_out) + P (f16, LDS)
  float* ab = attn_out + ((size_t)bh * 1024 + q0) * 1024;
#pragma unroll
  for (int mi = 0; mi < 2; mi++)
#pragma unroll
    for (int kt = 0; kt < 16; kt++)
#pragma unroll
      for (int r = 0; r < 4; r++) {
        int row = mi * 16 + lg * 4 + r;
        int col = kw + kt * 16 + l15;
        float a = sc[mi][kt][r] * inv[mi][r];
        ab[(size_t)row * 1024 + col] = a;
        P[wave][row][kt * 16 + l15] = (_Float16)a;
      }
  __syncthreads();
  // PV: ctx[32][64] partial per wave over its 256-key strip
  f32x4 ctx[2][4];
#pragma unroll
  for (int mi = 0; mi < 2; mi++)
#pragma unroll
    for (int fj = 0; fj < 4; fj++) ctx[mi][fj] = (f32x4){0.f, 0.f, 0.f, 0.f};
  const __half* Vb = Vt + (size_t)bh * 64 * 1024 + kw;
#pragma unroll
  for (int kk = 0; kk < 8; kk++) {
    f16x8 pa[2];
#pragma unroll
    for (int mi = 0; mi < 2; mi++)
      pa[mi] = *(const f16x8*)&P[wave][mi * 16 + l15][kk * 32 + lg * 8];
#pragma unroll
    for (int fj = 0; fj < 4; fj++) {
      f16x8 vf = *(const f16x8*)(Vb + (size_t)(fj * 16 + l15) * 1024 + kk * 32 + lg * 8);
#pragma unroll
      for (int mi = 0; mi < 2; mi++)
        ctx[mi][fj] = __builtin_amdgcn_mfma_f32_16x16x32_f16(pa[mi], vf, ctx[mi][fj], 0, 0, 0);
    }
  }
  __syncthreads();  // all waves done reading P; reuse as f32 reduce buffer
  float(*cr)[32][64] = (float(*)[32][64]) & P[0][0][0];
#pragma unroll
  for (int mi = 0; mi < 2; mi++)
#pragma unroll
    for (int fj = 0; fj < 4; fj++)
#pragma unroll
      for (int r = 0; r < 4; r++)
        cr[wave][mi * 16 + lg * 4 + r][fj * 16 + l15] = ctx[mi][fj][r];
  __syncthreads();
  {
    int row = tid >> 3;
    int dv0 = (tid & 7) * 8;
    __half* Cb = CTX + (size_t)(b * 1024 + q0 + row) * 512 + h * 64 + dv0;
#pragma unroll
    for (int i = 0; i < 8; i++) {
      float s = cr[0][row][dv0 + i] + cr[1][row][dv0 + i] + cr[2][row][dv0 + i] +
                cr[3][row][dv0 + i];
      Cb[i] = __float2half(s);
    }
  }
}

// ---------- residual + LayerNorm ----------
__global__ __launch_bounds__(256) void ln_kernel(const __half* __restrict__ O,
                                                 const float* __restrict__ resid,
                                                 const float* __restrict__ g,
                                                 const float* __restrict__ bb,
                                                 float* __restrict__ out) {
  int row = blockIdx.x, tid = threadIdx.x;
  int wv = tid >> 6, lane = tid & 63;
  size_t base = (size_t)row * 512;
  float x0 = __half2float(O[base + tid]) + resid[base + tid];
  float x1 = __half2float(O[base + tid + 256]) + resid[base + tid + 256];
  __shared__ float red[4];
  float s = x0 + x1;
#pragma unroll
  for (int o = 1; o < 64; o <<= 1) s += __shfl_xor(s, o);
  if (lane == 0) red[wv] = s;
  __syncthreads();
  float mean = (red[0] + red[1] + red[2] + red[3]) * (1.0f / 512.0f);
  __syncthreads();
  float d0 = x0 - mean, d1 = x1 - mean;
  float v = d0 * d0 + d1 * d1;
#pragma unroll
  for (int o = 1; o < 64; o <<= 1) v += __shfl_xor(v, o);
  if (lane == 0) red[wv] = v;
  __syncthreads();
  float var = (red[0] + red[1] + red[2] + red[3]) * (1.0f / 512.0f);
  float rs = rsqrtf(var + 1e-5f);
  out[base + tid] = d0 * rs * g[tid] + bb[tid];
  out[base + tid + 256] = d1 * rs * g[tid + 256] + bb[tid + 256];
}

extern "C" void kernel_launch(void* const* d_in, const int* in_sizes, int n_in,
                              void* d_out, int out_size, void* d_ws, size_t ws_size,
                              hipStream_t stream) {
  const float* inQ = (const float*)d_in[0];
  const float* inK = (const float*)d_in[1];
  const float* inV = (const float*)d_in[2];
  const int* am = (const int*)d_in[3];
  const int* bmk = (const int*)d_in[4];
  const float* Wq = (const float*)d_in[5];
  const float* Wk = (const float*)d_in[6];
  const float* Wq2 = (const float*)d_in[7];
  const float* Wk2 = (const float*)d_in[8];
  const float* Wv = (const float*)d_in[9];
  const float* Wo = (const float*)d_in[10];
  const float* lng = (const float*)d_in[11];
  const float* lnb = (const float*)d_in[12];

  char* ws = (char*)d_ws;
  __half* WqcT = (__half*)ws; ws += (size_t)1024 * 512 * 2;
  __half* WkcT = (__half*)ws; ws += (size_t)1024 * 512 * 2;
  __half* WvT = (__half*)ws;  ws += (size_t)512 * 512 * 2;
  __half* WoT = (__half*)ws;  ws += (size_t)512 * 512 * 2;
  __half* QQ2 = (__half*)ws;  ws += (size_t)4096 * 1024 * 2;
  __half* KK2 = (__half*)ws;  ws += (size_t)4096 * 1024 * 2;
  __half* Vout = (__half*)ws; ws += (size_t)4096 * 512 * 2;
  __half* Vt = (__half*)ws;   ws += (size_t)4096 * 512 * 2;
  __half* CTX = (__half*)ws;  ws += (size_t)4096 * 512 * 2;
  __half* Obuf = (__half*)ws; ws += (size_t)4096 * 512 * 2;

  float* out0 = (float*)d_out;
  float* attn_out = out0 + (size_t)4 * 1024 * 512;  // 2,097,152

  dim3 tb(32, 8);
  wtrans_kernel<<<dim3(16, 16), tb, 0, stream>>>(Wq, WqcT);
  wtrans_kernel<<<dim3(16, 16), tb, 0, stream>>>(Wq2, WqcT + 512 * 512);
  wtrans_kernel<<<dim3(16, 16), tb, 0, stream>>>(Wk, WkcT);
  wtrans_kernel<<<dim3(16, 16), tb, 0, stream>>>(Wk2, WkcT + 512 * 512);
  wtrans_kernel<<<dim3(16, 16), tb, 0, stream>>>(Wv, WvT);
  wtrans_kernel<<<dim3(16, 16), tb, 0, stream>>>(Wo, WoT);

  gemm_kernel<1><<<dim3(8, 32), 256, 0, stream>>>(inQ, WqcT, QQ2, 1024);
  gemm_kernel<1><<<dim3(8, 32), 256, 0, stream>>>(inK, WkcT, KK2, 1024);
  gemm_kernel<1><<<dim3(4, 32), 256, 0, stream>>>(inV, WvT, Vout, 512);

  vtrans_kernel<<<dim3(16, 32), dim3(64, 4), 0, stream>>>(Vout, Vt);

  attn_kernel<<<dim3(32, 32), 256, 0, stream>>>(QQ2, KK2, Vt, am, bmk, attn_out, CTX);

  gemm_kernel<0><<<dim3(4, 32), 256, 0, stream>>>(CTX, WoT, Obuf, 512);

  ln_kernel<<<4096, 256, 0, stream>>>(Obuf, inQ, lng, lnb, out0);
}